// Round 1
// baseline (301.106 us; speedup 1.0000x reference)
//
#include <hip/hip_runtime.h>
#include <hip/hip_bf16.h>
#include <math.h>

#define DIM 128
#define DFF 512
#define TTW 64
#define NPI 8
#define NTOK 9
#define TILE_H 32

typedef __attribute__((ext_vector_type(8))) short short8;
typedef __attribute__((ext_vector_type(4))) float float4v;

__device__ __forceinline__ float bf16lo_f32(unsigned u) {
    union { unsigned u; float f; } v; v.u = u << 16;
    return v.f;
}
__device__ __forceinline__ float bf16hi_f32(unsigned u) {
    union { unsigned u; float f; } v; v.u = u & 0xffff0000u;
    return v.f;
}
__device__ __forceinline__ unsigned pk_bf16(float a, float b) {  // -> a | b<<16
    __hip_bfloat162 h = __float22bfloat162_rn(float2{a, b});
    union { __hip_bfloat162 h; unsigned u; } cv; cv.h = h;
    return cv.u;
}

// ============ prep (slim): hf->bf16 (8 elems/thread) + W1/W2 transposes ============
__global__ __launch_bounds__(256)
void prep_k(const float* __restrict__ hf, const float* __restrict__ W1,
            const float* __restrict__ W2,
            unsigned short* __restrict__ hf2, unsigned short* __restrict__ w1t,
            unsigned short* __restrict__ w2t,
            int n_hf, int B_HF)
{
    __shared__ float tile[32][33];
    const int b = blockIdx.x, t = threadIdx.x;
    if (b < B_HF) {
        int i = (b * 256 + t) * 8;
        if (i < n_hf) {
            float4v v0 = *(const float4v*)(hf + i);
            float4v v1 = *(const float4v*)(hf + i + 4);
            uint4 o;
            o.x = pk_bf16(v0[0], v0[1]);
            o.y = pk_bf16(v0[2], v0[3]);
            o.z = pk_bf16(v1[0], v1[1]);
            o.w = pk_bf16(v1[2], v1[3]);
            *(uint4*)(hf2 + i) = o;
        }
    } else if (b < B_HF + 64) {
        const int tb = b - B_HF;            // W1 [128][512] -> w1t bf16 [512][128]
        const int r0 = (tb & 3) * 32, c0 = (tb >> 2) * 32;
        const int ty = t >> 3, tx = t & 7;
        *(float4v*)&tile[ty][tx * 4] = *(const float4v*)(W1 + (r0 + ty) * DFF + c0 + tx * 4);
        __syncthreads();
        uint2 o;
        o.x = pk_bf16(tile[tx * 4 + 0][ty], tile[tx * 4 + 1][ty]);
        o.y = pk_bf16(tile[tx * 4 + 2][ty], tile[tx * 4 + 3][ty]);
        *(uint2*)(w1t + (c0 + ty) * DIM + r0 + tx * 4) = o;
    } else {
        const int tb = b - B_HF - 64;       // W2 [512][64] -> w2t bf16 [64][512]
        const int r0 = (tb & 15) * 32, c0 = (tb >> 4) * 32;
        const int ty = t >> 3, tx = t & 7;
        *(float4v*)&tile[ty][tx * 4] = *(const float4v*)(W2 + (r0 + ty) * TTW + c0 + tx * 4);
        __syncthreads();
        uint2 o;
        o.x = pk_bf16(tile[tx * 4 + 0][ty], tile[tx * 4 + 1][ty]);
        o.y = pk_bf16(tile[tx * 4 + 2][ty], tile[tx * 4 + 3][ty]);
        *(uint2*)(w2t + (c0 + ty) * DFF + r0 + tx * 4) = o;
    }
}

// ===== fused: gather+pool (hoisted loads) -> GEMM1 -> reg-LN -> k-split GEMM2 =====
// Occupancy was LDS-limited: 43008 B -> 3 blocks/CU = 12/32 waves (Occ 30%,
// latency-bound: MfmaUtil 6.5%, VALU 34%, bank-conflicts negligible).
// Fix: GEMM2 runs in two K=256 chunks through a half-width Hsm buffer, and
// GEMM1's output-dim ownership is re-striped to mt*64 + w*16 so chunk c needs
// exactly mt in [4c, 4c+4) from every wave. LDS 43008 -> 26624 B -> 6 blocks/CU
// = 24 waves. __launch_bounds__(256,6) caps VGPR at 85 (usage was 68; if
// WRITE_SIZE blows up it spilled -> back off to 5).
__global__ __launch_bounds__(256, 6)
void fused_k(const unsigned short* __restrict__ hf2,
             const float* __restrict__ w_q,
             const int* __restrict__ pi,
             const int* __restrict__ stats,
             const int* __restrict__ po,
             const unsigned short* __restrict__ w1t,     // bf16 [512][128]
             const float* __restrict__ b1,
             const float* __restrict__ gamma,
             const float* __restrict__ beta,
             const unsigned short* __restrict__ w2t,     // bf16 [64][512]
             const float* __restrict__ b2,
             float* __restrict__ out,
             int H)
{
    __shared__ __align__(16) unsigned short Apool[TILE_H][DIM + 8];   // 8704 B
    __shared__ __align__(16) unsigned short Hsm[TILE_H][256 + 8];     // 16896 B
    __shared__ float part[2][16][4][2];                 // [ht][row][wave][sum,ssq]

    const int t    = threadIdx.x;
    const int lane = t & 63;
    const int w    = t >> 6;
    const int row  = lane & 15;
    const int quad = lane >> 4;
    const int hop0 = blockIdx.x * TILE_H;

    // -------- Phase 1: gather + masked attention pooling (32 lanes/hop) --------
    // All 36 token loads issued back-to-back BEFORE any softmax compute so their
    // ~200-900 cyc latency overlaps (fine-grained vmcnt waits at first use).
    {
        const int g = t >> 5, l = t & 31;       // lane l owns dims 4l..4l+3
        const float4v wq4 = *(const float4v*)(w_q + l * 4);

        int idxs[4][NTOK];
        unsigned vm[4];
        #pragma unroll
        for (int it = 0; it < 4; ++it) {
            int hop = hop0 + g + it * 8;
            if (hop >= H) hop = H - 1;          // clamp; out stores are guarded
            int4 p0 = *(const int4*)(pi + hop * NPI);
            int4 p1 = *(const int4*)(pi + hop * NPI + 4);
            int4 s0 = *(const int4*)(stats + hop * NPI);
            int4 s1 = *(const int4*)(stats + hop * NPI + 4);
            idxs[it][0] = p0.x; idxs[it][1] = p0.y;
            idxs[it][2] = p0.z; idxs[it][3] = p0.w;
            idxs[it][4] = p1.x; idxs[it][5] = p1.y;
            idxs[it][6] = p1.z; idxs[it][7] = p1.w;
            idxs[it][8] = po[hop];
            vm[it] = (s0.x != -1 ? 1u   : 0u) | (s0.y != -1 ? 2u   : 0u)
                   | (s0.z != -1 ? 4u   : 0u) | (s0.w != -1 ? 8u   : 0u)
                   | (s1.x != -1 ? 16u  : 0u) | (s1.y != -1 ? 32u  : 0u)
                   | (s1.z != -1 ? 64u  : 0u) | (s1.w != -1 ? 128u : 0u)
                   | 256u;                      // PO always valid
        }
        uint2 tu[4][NTOK];                      // 72 VGPRs; acc not yet live
        #pragma unroll
        for (int it = 0; it < 4; ++it)
            #pragma unroll
            for (int p = 0; p < NTOK; ++p)
                tu[it][p] = *(const uint2*)(hf2 + (size_t)idxs[it][p] * DIM + l * 4);

        #pragma unroll
        for (int it = 0; it < 4; ++it) {
            const int hl = g + it * 8;
            float tok[NTOK][4];
            #pragma unroll
            for (int p = 0; p < NTOK; ++p) {
                tok[p][0] = bf16lo_f32(tu[it][p].x);
                tok[p][1] = bf16hi_f32(tu[it][p].x);
                tok[p][2] = bf16lo_f32(tu[it][p].y);
                tok[p][3] = bf16hi_f32(tu[it][p].y);
            }
            float sc[NTOK];
            #pragma unroll
            for (int p = 0; p < NTOK; ++p)
                sc[p] = tok[p][0]*wq4[0] + tok[p][1]*wq4[1]
                      + tok[p][2]*wq4[2] + tok[p][3]*wq4[3];
            #pragma unroll
            for (int m = 1; m < 32; m <<= 1) {
                #pragma unroll
                for (int p = 0; p < NTOK; ++p) sc[p] += __shfl_xor(sc[p], m);
            }
            const float isd = 0.08838834764831845f;   // 1/sqrt(128)
            float mx = -1e30f;
            #pragma unroll
            for (int p = 0; p < NTOK; ++p) {
                sc[p] = ((vm[it] >> p) & 1u) ? sc[p] * isd : -1e30f;
                mx = fmaxf(mx, sc[p]);
            }
            float se = 0.f;
            #pragma unroll
            for (int p = 0; p < NTOK; ++p) { sc[p] = __expf(sc[p] - mx); se += sc[p]; }
            const float inv = 1.f / se;
            float a0=0.f, a1=0.f, a2=0.f, a3=0.f;
            #pragma unroll
            for (int p = 0; p < NTOK; ++p) {
                float a = sc[p] * inv;
                a0 += a * tok[p][0]; a1 += a * tok[p][1];
                a2 += a * tok[p][2]; a3 += a * tok[p][3];
            }
            uint2 o;
            o.x = pk_bf16(a0, a1);
            o.y = pk_bf16(a2, a3);
            *(uint2*)&Apool[hl][l * 4] = o;
        }
    }
    __syncthreads();

    // -------- GEMM1: A=W1T rows (out-dims, striped mt*64+w*16), B=Apool^T --------
    float4v acc[8][2];
    #pragma unroll
    for (int mt = 0; mt < 8; ++mt) {
        acc[mt][0] = (float4v){0.f, 0.f, 0.f, 0.f};
        acc[mt][1] = (float4v){0.f, 0.f, 0.f, 0.f};
    }
    {
        short8 bfr[2][4];
        #pragma unroll
        for (int ks = 0; ks < 4; ++ks) {
            const int k0 = ks * 32 + quad * 8;
            #pragma unroll
            for (int ht = 0; ht < 2; ++ht)
                bfr[ht][ks] = *(const short8*)&Apool[ht * 16 + row][k0];
        }
        #pragma unroll
        for (int mt = 0; mt < 8; ++mt) {
            const unsigned short* wrow = w1t + (size_t)(mt * 64 + w * 16 + row) * DIM;
            #pragma unroll
            for (int ks = 0; ks < 4; ++ks) {
                short8 afr = *(const short8*)(wrow + ks * 32 + quad * 8);
                acc[mt][0] = __builtin_amdgcn_mfma_f32_16x16x32_bf16(afr, bfr[0][ks], acc[mt][0], 0, 0, 0);
                acc[mt][1] = __builtin_amdgcn_mfma_f32_16x16x32_bf16(afr, bfr[1][ks], acc[mt][1], 0, 0, 0);
            }
        }
    }
    // -------- pass 1: bias + ReLU in registers, LN stats --------
    float sum0 = 0.f, ssq0 = 0.f, sum1 = 0.f, ssq1 = 0.f;
    #pragma unroll
    for (int mt = 0; mt < 8; ++mt) {
        const int nb = mt * 64 + w * 16 + quad * 4;
        const float4v bias = *(const float4v*)(b1 + nb);
        #pragma unroll
        for (int r = 0; r < 4; ++r) {
            float v0 = fmaxf(acc[mt][0][r] + bias[r], 0.f);
            float v1 = fmaxf(acc[mt][1][r] + bias[r], 0.f);
            acc[mt][0][r] = v0;  sum0 += v0;  ssq0 += v0 * v0;
            acc[mt][1][r] = v1;  sum1 += v1;  ssq1 += v1 * v1;
        }
    }
    #pragma unroll
    for (int m = 16; m <= 32; m <<= 1) {       // reduce across the 4 quads
        sum0 += __shfl_xor(sum0, m);  ssq0 += __shfl_xor(ssq0, m);
        sum1 += __shfl_xor(sum1, m);  ssq1 += __shfl_xor(ssq1, m);
    }
    if (lane < 16) {
        part[0][row][w][0] = sum0;  part[0][row][w][1] = ssq0;
        part[1][row][w][0] = sum1;  part[1][row][w][1] = ssq1;
    }
    __syncthreads();
    float mu[2], rs[2];
    #pragma unroll
    for (int ht = 0; ht < 2; ++ht) {
        float S = 0.f, Q = 0.f;
        #pragma unroll
        for (int ww = 0; ww < 4; ++ww) {
            S += part[ht][row][ww][0];
            Q += part[ht][row][ww][1];
        }
        const float invn = 1.f / (float)DFF;
        mu[ht] = S * invn;
        float var = Q * invn - mu[ht] * mu[ht];
        rs[ht] = rsqrtf(var + 1e-5f);
    }
    // -------- pass 2 + GEMM2, k-split into two 256-wide chunks through Hsm ------
    {
        float4v acc2[2];
        acc2[0] = (float4v){0.f,0.f,0.f,0.f};
        acc2[1] = (float4v){0.f,0.f,0.f,0.f};
        #pragma unroll
        for (int c = 0; c < 2; ++c) {
            // normalize chunk's dims (mt = 4c..4c+3) in regs, pack bf16, LDS write
            #pragma unroll
            for (int m4 = 0; m4 < 4; ++m4) {
                const int mt  = c * 4 + m4;
                const int nb  = mt * 64 + w * 16 + quad * 4;    // global dim
                const int col = m4 * 64 + w * 16 + quad * 4;    // col within chunk
                const float4v g4  = *(const float4v*)(gamma + nb);
                const float4v be4 = *(const float4v*)(beta + nb);
                #pragma unroll
                for (int ht = 0; ht < 2; ++ht) {
                    float o[4];
                    #pragma unroll
                    for (int r = 0; r < 4; ++r) {
                        float tg = rs[ht] * g4[r];
                        o[r] = acc[mt][ht][r] * tg + (be4[r] - mu[ht] * tg);
                    }
                    uint2 p;
                    p.x = pk_bf16(o[0], o[1]);
                    p.y = pk_bf16(o[2], o[3]);
                    *(uint2*)&Hsm[ht * 16 + row][col] = p;
                }
            }
            __syncthreads();
            // accumulate this k-chunk: A=Hsm [hop][k] LDS, B=w2t [tt][k] global
            const unsigned short* w2row = w2t + (size_t)(w * 16 + row) * DFF + c * 256;
            #pragma unroll
            for (int ks = 0; ks < 8; ++ks) {
                const int k0 = ks * 32 + quad * 8;
                short8 bfr = *(const short8*)(w2row + k0);
                #pragma unroll
                for (int mt = 0; mt < 2; ++mt) {
                    short8 afr = *(const short8*)&Hsm[mt * 16 + row][k0];
                    acc2[mt] = __builtin_amdgcn_mfma_f32_16x16x32_bf16(
                        afr, bfr, acc2[mt], 0, 0, 0);
                }
            }
            if (c == 0) __syncthreads();   // all reads done before chunk-1 writes
        }
        const float bb = b2[w * 16 + row];
        #pragma unroll
        for (int mt = 0; mt < 2; ++mt) {
            #pragma unroll
            for (int r = 0; r < 4; ++r) {
                int hop = hop0 + mt * 16 + quad * 4 + r;
                if (hop < H)
                    out[(size_t)hop * TTW + w * 16 + row] = acc2[mt][r] + bb;
            }
        }
    }
}

extern "C" void kernel_launch(void* const* d_in, const int* in_sizes, int n_in,
                              void* d_out, int out_size, void* d_ws, size_t ws_size,
                              hipStream_t stream) {
    const float* hf    = (const float*)d_in[0];
    const float* w_q   = (const float*)d_in[1];
    const float* W1    = (const float*)d_in[2];
    const float* b1    = (const float*)d_in[3];
    const float* gamma = (const float*)d_in[4];
    const float* beta  = (const float*)d_in[5];
    const float* W2    = (const float*)d_in[6];
    const float* b2    = (const float*)d_in[7];
    const int* pi      = (const int*)d_in[8];
    const int* stats   = (const int*)d_in[9];
    const int* po      = (const int*)d_in[10];
    float* out         = (float*)d_out;

    const int n_hf = in_sizes[0];           // N_NODES*128
    const int H    = in_sizes[10];
    const int ntiles = (H + TILE_H - 1) / TILE_H;

    // ws layout
    char* ws = (char*)d_ws;
    unsigned short* w1t = (unsigned short*)ws;                       // 128KB
    unsigned short* w2t = (unsigned short*)(ws + 131072);            // 64KB
    unsigned short* hf2 = (unsigned short*)(ws + 196608);            // n_hf*2

    const int B_HF = (n_hf + 2047) / 2048;   // 8 elems/thread
    hipLaunchKernelGGL(prep_k, dim3(B_HF + 96), dim3(256), 0, stream,
                       hf, W1, W2, hf2, w1t, w2t, n_hf, B_HF);
    hipLaunchKernelGGL(fused_k, dim3(ntiles), dim3(256), 0, stream,
                       hf2, w_q, pi, stats, po, w1t, b1, gamma, beta, w2t, b2, out, H);
}